// Round 1
// baseline (387.159 us; speedup 1.0000x reference)
//
#include <hip/hip_runtime.h>

// ---------------------------------------------------------------------------
// DomainAlignmentModel: 3-branch GCN-ish model on MI355X.
// Identity used: spmm(x) @ W == spmm(x @ W)  -> project first (128->64),
// fuse homo+het projected features into one N x 128 buffer, 1 SPMM per layer.
// Adjacency: y[i] = dinv[i]*( sum_{c in nbr(i)} dinv[c]*P[c] + dinv[i]*P[i] )
// with deg = in-degree(col)+1 (self loop), dinv = rsqrt(deg).
// ---------------------------------------------------------------------------

__global__ __launch_bounds__(256) void build_adj_kernel(
    const int* __restrict__ ei, int E, int* __restrict__ deg,
    int* __restrict__ cur, int* __restrict__ bucket)
{
    int e = blockIdx.x * 256 + threadIdx.x;
    if (e >= E) return;
    int r = ei[e];          // edge_index[0][e]  (dest of the scatter-add)
    int c = ei[E + e];      // edge_index[1][e]  (source / degree node)
    atomicAdd(&deg[c], 1);
    int pos = atomicAdd(&cur[r], 1);
    if (pos < 64) bucket[(size_t)r * 64 + pos] = c;
}

__global__ __launch_bounds__(256) void dinv_kernel(
    const int* __restrict__ deg, float* __restrict__ dinv, int N)
{
    int i = blockIdx.x * 256 + threadIdx.x;
    if (i < N) dinv[i] = 1.0f / sqrtf((float)deg[i] + 1.0f);
}

// One wave per 16 rows; lane = output column (0..63). W column kept in VGPRs,
// x row elements are wave-uniform -> scalar loads. blockIdx.y = branch:
//   b=0 -> outP[:,0:64] (no epilogue), b=1 -> outP[:,64:128] (no epilogue),
//   b=2 -> outF[:,0:64] with relu(alpha*v).
template<int K>
__global__ __launch_bounds__(256) void gemm3_kernel(
    const float* __restrict__ in0, const float* __restrict__ in1, const float* __restrict__ in2,
    const float* __restrict__ w0, const float* __restrict__ w1, const float* __restrict__ w2,
    float* __restrict__ outP, float* __restrict__ outF,
    const float* __restrict__ alphaF, int N)
{
    const int b = blockIdx.y;
    const float* __restrict__ in = (b == 0) ? in0 : ((b == 1) ? in1 : in2);
    const float* __restrict__ W  = (b == 0) ? w0  : ((b == 1) ? w1  : w2);
    const int lane = threadIdx.x & 63;
    int row0v = blockIdx.x * 64 + (threadIdx.x >> 6) * 16;
    const int row0 = __builtin_amdgcn_readfirstlane(row0v);
    if (row0 >= N) return;

    float wreg[K];
    #pragma unroll
    for (int k = 0; k < K; ++k) wreg[k] = W[(size_t)k * 64 + lane];

    const int rmax = (N - row0 < 16) ? (N - row0) : 16;
    const float alpha = alphaF[0];
    for (int r = 0; r < rmax; ++r) {
        const int row = row0 + r;
        const float* __restrict__ xr = in + (size_t)row * K;
        float a0 = 0.f, a1 = 0.f, a2 = 0.f, a3 = 0.f;
        #pragma unroll
        for (int k = 0; k < K; k += 4) {
            a0 += xr[k + 0] * wreg[k + 0];
            a1 += xr[k + 1] * wreg[k + 1];
            a2 += xr[k + 2] * wreg[k + 2];
            a3 += xr[k + 3] * wreg[k + 3];
        }
        float v = (a0 + a1) + (a2 + a3);
        if (b < 2) {
            outP[(size_t)row * 128 + b * 64 + lane] = v;
        } else {
            outF[(size_t)row * 64 + lane] = fmaxf(alpha * v, 0.f);
        }
    }
}

// SPMM over fused N x 128 features. One wave per dest node; lane holds
// features (2*lane, 2*lane+1) as float2. Lanes 0-31 -> homo half, 32-63 -> het.
__global__ __launch_bounds__(256) void spmm1_kernel(
    const float* __restrict__ P, const int* __restrict__ bucket, const int* __restrict__ cnt,
    const float* __restrict__ dinv, float* __restrict__ homo1, float* __restrict__ het1,
    const float* __restrict__ aH, const float* __restrict__ aT, int N)
{
    const int i = blockIdx.x * 4 + (threadIdx.x >> 6);
    if (i >= N) return;
    const int lane = threadIdx.x & 63;
    const float2* __restrict__ P2 = (const float2*)P;
    const float di = dinv[i];
    const float2 ps = P2[(size_t)i * 64 + lane];
    int n = cnt[i]; if (n > 64) n = 64;
    const int* __restrict__ brow = bucket + (size_t)i * 64;
    float ax = 0.f, ay = 0.f;
    for (int k0 = 0; k0 < n; k0 += 8) {
        #pragma unroll
        for (int j = 0; j < 8; ++j) {
            const int k = k0 + j;
            const bool act = (k < n);
            const int c = act ? brow[k] : i;       // broadcast load (uniform)
            const float dc = act ? dinv[c] : 0.f;  // broadcast gather
            const float2 v = P2[(size_t)c * 64 + lane];
            ax += dc * v.x; ay += dc * v.y;
        }
    }
    const float yx = di * (ax + di * ps.x);
    const float yy = di * (ay + di * ps.y);
    float ox, oy; float* dst;
    if (lane < 32) {
        const float a = aH[0];
        ox = fmaxf(a * yx, 0.f); oy = fmaxf(a * yy, 0.f);
        dst = homo1 + (size_t)i * 64 + 2 * lane;
    } else {
        const float a = aT[0];
        ox = fmaxf(a * (ps.x - yx), 0.f); oy = fmaxf(a * (ps.y - yy), 0.f);
        dst = het1 + (size_t)i * 64 + 2 * (lane - 32);
    }
    *(float2*)dst = make_float2(ox, oy);
}

__global__ __launch_bounds__(256) void spmm2_kernel(
    const float* __restrict__ Q, const int* __restrict__ bucket, const int* __restrict__ cnt,
    const float* __restrict__ dinv, const float* __restrict__ full2,
    float* __restrict__ outComb, float* __restrict__ outHomo, float* __restrict__ outHet,
    const float* __restrict__ aH, const float* __restrict__ aT,
    const float* __restrict__ wH, const float* __restrict__ wF, const float* __restrict__ wT,
    int N)
{
    const int i = blockIdx.x * 4 + (threadIdx.x >> 6);
    if (i >= N) return;
    const int lane = threadIdx.x & 63;
    const float2* __restrict__ Q2 = (const float2*)Q;
    const float di = dinv[i];
    const float2 qs = Q2[(size_t)i * 64 + lane];
    int n = cnt[i]; if (n > 64) n = 64;
    const int* __restrict__ brow = bucket + (size_t)i * 64;
    float ax = 0.f, ay = 0.f;
    for (int k0 = 0; k0 < n; k0 += 8) {
        #pragma unroll
        for (int j = 0; j < 8; ++j) {
            const int k = k0 + j;
            const bool act = (k < n);
            const int c = act ? brow[k] : i;
            const float dc = act ? dinv[c] : 0.f;
            const float2 v = Q2[(size_t)c * 64 + lane];
            ax += dc * v.x; ay += dc * v.y;
        }
    }
    const float yx = di * (ax + di * qs.x);
    const float yy = di * (ay + di * qs.y);
    float vx, vy; float* dst;
    if (lane < 32) {
        const float a = aH[0];
        vx = fmaxf(a * yx, 0.f); vy = fmaxf(a * yy, 0.f);
        dst = outHomo + (size_t)i * 64 + 2 * lane;
    } else {
        const float a = aT[0];
        vx = fmaxf(a * (qs.x - yx), 0.f); vy = fmaxf(a * (qs.y - yy), 0.f);
        dst = outHet + (size_t)i * 64 + 2 * (lane - 32);
    }
    *(float2*)dst = make_float2(vx, vy);
    // combined = wH*h_homo + wF*h_full + wT*h_het; exchange halves across lane^32
    const float tx = __shfl_xor(vx, 32);
    const float ty = __shfl_xor(vy, 32);
    if (lane < 32) {
        const float2 f2 = ((const float2*)full2)[(size_t)i * 32 + lane];
        const float cwh = wH[0], cwf = wF[0], cwt = wT[0];
        const float cx = cwh * vx + cwf * f2.x + cwt * tx;
        const float cy = cwh * vy + cwf * f2.y + cwt * ty;
        *(float2*)(outComb + (size_t)i * 64 + 2 * lane) = make_float2(cx, cy);
    }
}

extern "C" void kernel_launch(void* const* d_in, const int* in_sizes, int n_in,
                              void* d_out, int out_size, void* d_ws, size_t ws_size,
                              hipStream_t stream)
{
    const float* x  = (const float*)d_in[0];
    const int*   ei = (const int*)d_in[1];
    const int N = in_sizes[0] / 128;
    const int E = in_sizes[1] / 2;
    const float* homo_W0 = (const float*)d_in[3];
    const float* homo_W1 = (const float*)d_in[4];
    const float* full_W0 = (const float*)d_in[5];
    const float* full_W1 = (const float*)d_in[6];
    const float* het_W0  = (const float*)d_in[7];
    const float* het_W1  = (const float*)d_in[8];
    const float* homo_a0 = (const float*)d_in[9];
    const float* homo_a1 = (const float*)d_in[10];
    const float* full_a0 = (const float*)d_in[11];
    const float* full_a1 = (const float*)d_in[12];
    const float* het_a0  = (const float*)d_in[13];
    const float* het_a1  = (const float*)d_in[14];
    const float* w_homo  = (const float*)d_in[15];
    const float* w_full  = (const float*)d_in[16];
    const float* w_het   = (const float*)d_in[17];

    char* ws = (char*)d_ws;
    size_t off = 0;
    auto alloc = [&](size_t bytes) -> char* {
        char* p = ws + off;
        off = (off + bytes + 511) & ~(size_t)511;
        return p;
    };
    int*   deg    = (int*)alloc((size_t)N * 4);
    int*   cur    = (int*)alloc((size_t)N * 4);
    float* dinv   = (float*)alloc((size_t)N * 4);
    int*   bucket = (int*)alloc((size_t)N * 64 * 4);
    float* P      = (float*)alloc((size_t)N * 128 * 4);
    float* full1  = (float*)alloc((size_t)N * 64 * 4);
    float* homo1  = (float*)alloc((size_t)N * 64 * 4);
    float* het1   = (float*)alloc((size_t)N * 64 * 4);
    float* Q      = P;  // P dead after spmm1; reuse for layer-2 fused features

    float* out      = (float*)d_out;
    float* outComb  = out;
    float* outHomo  = out + (size_t)N * 64;
    float* outFull  = out + (size_t)2 * N * 64;
    float* outHet   = out + (size_t)3 * N * 64;

    hipMemsetAsync(deg, 0, (size_t)N * 4, stream);
    hipMemsetAsync(cur, 0, (size_t)N * 4, stream);

    build_adj_kernel<<<(E + 255) / 256, 256, 0, stream>>>(ei, E, deg, cur, bucket);
    dinv_kernel<<<(N + 255) / 256, 256, 0, stream>>>(deg, dinv, N);

    // Layer 1: P[:,0:64]=x@homo_W0, P[:,64:128]=x@het_W0, full1=relu(af0*x@full_W0)
    gemm3_kernel<128><<<dim3((N + 63) / 64, 3), 256, 0, stream>>>(
        x, x, x, homo_W0, het_W0, full_W0, P, full1, full_a0, N);
    spmm1_kernel<<<(N + 3) / 4, 256, 0, stream>>>(
        P, bucket, cur, dinv, homo1, het1, homo_a0, het_a0, N);

    // Layer 2: Q[:,0:64]=homo1@homo_W1, Q[:,64:128]=het1@het_W1,
    //          h_full = relu(af1*full1@full_W1) written straight to d_out
    gemm3_kernel<64><<<dim3((N + 63) / 64, 3), 256, 0, stream>>>(
        homo1, het1, full1, homo_W1, het_W1, full_W1, Q, outFull, full_a1, N);
    spmm2_kernel<<<(N + 3) / 4, 256, 0, stream>>>(
        Q, bucket, cur, dinv, outFull, outComb, outHomo, outHet,
        homo_a1, het_a1, w_homo, w_full, w_het, N);
}